// Round 4
// baseline (208.657 us; speedup 1.0000x reference)
//
#include <hip/hip_runtime.h>
#include <hip/hip_bf16.h>

// Guided filter, B=8 C=3 H=W=512, RADIUS=15 (31x31 box, zero-pad, /961).
// R4: H-pass = wave64 DPP prefix scan (pure VALU, no raw halo in LDS);
//     h-sum(c) = P[c+31]-P[c] via one shuffle; only 62x32 float2 h-sums in
//     LDS (odd float2 stride -> conflict-free b64). V-pass slides as before.
//     LDS 47->33 KB (4 blocks/CU), barriers 8->4, gray cached in registers.

#define HW 512
#define PLANE 262144
#define RAD 15
#define TILE 32
#define NROWS 62          // TILE + 2*RAD window rows
#define HS2 33            // h row stride in float2 (odd -> conflict-free)
#define INV_K2 (1.0f / 961.0f)

template<int CTRL, int RM>
__device__ __forceinline__ float sstep(float x) {
    int s = __builtin_amdgcn_update_dpp(0, __float_as_int(x), CTRL, RM, 0xf, false);
    return x + __int_as_float(s);
}
// wave64 inclusive prefix sum, 6 DPP add-steps (VALU pipe only)
__device__ __forceinline__ float wscan(float x) {
    x = sstep<0x111, 0xf>(x);   // row_shr:1
    x = sstep<0x112, 0xf>(x);   // row_shr:2
    x = sstep<0x114, 0xf>(x);   // row_shr:4
    x = sstep<0x118, 0xf>(x);   // row_shr:8
    x = sstep<0x142, 0xa>(x);   // row_bcast:15 -> rows 1,3
    x = sstep<0x143, 0xc>(x);   // row_bcast:31 -> rows 2,3
    return x;
}

__global__ __launch_bounds__(256) void gf_stage1(
    const float* __restrict__ guide, const float* __restrict__ inp,
    float2* __restrict__ ab)
{
    __shared__ float2 hbuf[2][NROWS * HS2];

    const int tx0 = blockIdx.x * TILE, ty0 = blockIdx.y * TILE, b = blockIdx.z;
    const int tid  = threadIdx.x;
    const int lane = tid & 63, w = tid >> 6;      // wave 0..3 handles rows r%4==w
    const int xg   = tx0 - 16 + lane;             // lane -> x (64 consecutive)
    const bool xok = (unsigned)xg < (unsigned)HW;
    const int c31  = tid & 31;                    // output column within tile
    const int vq   = tid >> 5;                    // V-pass 4-row group 0..7

    const float* g0 = guide + (size_t)b * 3 * PLANE;
    const float* g1 = g0 + PLANE;
    const float* g2 = g0 + 2 * PLANE;
    const float* p0 = inp + (size_t)b * 3 * PLANE;

    float grr[16];   // gray value at (row-iter, lane), reused by all 3 channels

    // ---- H pass: gray (sum g, sum g^2) -> hbuf[0] ----
    #pragma unroll
    for (int it = 0; it < 16; ++it) {
        int r = it * 4 + w;
        int y = ty0 - RAD + r;
        float g = 0.f;
        if (r < NROWS && (unsigned)y < (unsigned)HW && xok) {
            int o = y * HW + xg;
            g = 0.299f * g0[o] + 0.587f * g1[o] + 0.114f * g2[o];
        }
        grr[it] = g;
        if (r < NROWS) {
            float P0 = wscan(g);
            float P1 = wscan(g * g);
            float q0 = __shfl(P0, c31 + 31);
            float q1 = __shfl(P1, c31 + 31);
            if (lane < 32)
                hbuf[0][r * HS2 + lane] = make_float2(q0 - P0, q1 - P1);
        }
    }
    __syncthreads();

    // ---- V gray -> mean_I, var_I (registers) ----
    float meanI[4], varI[4];
    {
        const float2* hp = hbuf[0];
        const int base = (vq * 4) * HS2 + c31;
        float s0 = 0.f, s1 = 0.f;
        #pragma unroll
        for (int k = 0; k < 31; ++k) { float2 v = hp[base + k * HS2]; s0 += v.x; s1 += v.y; }
        meanI[0] = s0 * INV_K2; varI[0] = s1 * INV_K2 - meanI[0] * meanI[0];
        #pragma unroll
        for (int j = 1; j < 4; ++j) {
            float2 vi = hp[base + (j + 30) * HS2], vo = hp[base + (j - 1) * HS2];
            s0 += vi.x - vo.x; s1 += vi.y - vo.y;
            meanI[j] = s0 * INV_K2; varI[j] = s1 * INV_K2 - meanI[j] * meanI[j];
        }
    }

#define H_CH(PP, BUF)                                                        \
    _Pragma("unroll")                                                        \
    for (int it = 0; it < 16; ++it) {                                        \
        int r = it * 4 + w;                                                  \
        int y = ty0 - RAD + r;                                               \
        float p = 0.f;                                                       \
        if (r < NROWS && (unsigned)y < (unsigned)HW && xok)                  \
            p = (PP)[y * HW + xg];                                           \
        if (r < NROWS) {                                                     \
            float P0 = wscan(p);                                             \
            float P1 = wscan(grr[it] * p);                                   \
            float q0 = __shfl(P0, c31 + 31);                                 \
            float q1 = __shfl(P1, c31 + 31);                                 \
            if (lane < 32)                                                   \
                hbuf[BUF][r * HS2 + lane] = make_float2(q0 - P0, q1 - P1);   \
        }                                                                    \
    }

#define V_CH(ch, BUF)                                                        \
    {                                                                        \
        const float2* hp = hbuf[BUF];                                        \
        const int base = (vq * 4) * HS2 + c31;                               \
        float s0 = 0.f, s1 = 0.f;                                            \
        _Pragma("unroll")                                                    \
        for (int k = 0; k < 31; ++k) { float2 v = hp[base + k * HS2]; s0 += v.x; s1 += v.y; } \
        float2* abp = ab + (size_t)(b * 3 + (ch)) * PLANE;                   \
        _Pragma("unroll")                                                    \
        for (int j = 0; j < 4; ++j) {                                        \
            if (j) {                                                         \
                float2 vi = hp[base + (j + 30) * HS2], vo = hp[base + (j - 1) * HS2]; \
                s0 += vi.x - vo.x; s1 += vi.y - vo.y;                        \
            }                                                                \
            float mp = s0 * INV_K2, corr = s1 * INV_K2;                      \
            float cov = corr - meanI[j] * mp;                                \
            float aa  = cov / (varI[j] + 1e-6f);                             \
            float bb  = mp - aa * meanI[j];                                  \
            abp[(ty0 + vq * 4 + j) * HW + tx0 + c31] = make_float2(aa, bb);  \
        }                                                                    \
    }

    // ping-pong: V(k) reads one buffer while H(k+1) fills the other
    H_CH(p0, 1)
    __syncthreads();
    V_CH(0, 1)
    H_CH(p0 + PLANE, 0)
    __syncthreads();
    V_CH(1, 0)
    H_CH(p0 + 2 * PLANE, 1)
    __syncthreads();
    V_CH(2, 1)
#undef H_CH
#undef V_CH
}

__global__ __launch_bounds__(256) void gf_stage2(
    const float* __restrict__ guide, const float2* __restrict__ ab,
    float* __restrict__ out)
{
    __shared__ float2 hbuf[NROWS * HS2];

    const int tx0 = blockIdx.x * TILE, ty0 = blockIdx.y * TILE;
    const int bc = blockIdx.z, b = bc / 3;
    const int tid = threadIdx.x, lane = tid & 63, w = tid >> 6;
    const int xg = tx0 - 16 + lane;
    const bool xok = (unsigned)xg < (unsigned)HW;
    const int c31 = tid & 31, vq = tid >> 5;

    const float2* abp = ab + (size_t)bc * PLANE;

    #pragma unroll
    for (int it = 0; it < 16; ++it) {
        int r = it * 4 + w;
        int y = ty0 - RAD + r;
        float2 v = make_float2(0.f, 0.f);
        if (r < NROWS && (unsigned)y < (unsigned)HW && xok)
            v = abp[y * HW + xg];
        if (r < NROWS) {
            float P0 = wscan(v.x);
            float P1 = wscan(v.y);
            float q0 = __shfl(P0, c31 + 31);
            float q1 = __shfl(P1, c31 + 31);
            if (lane < 32)
                hbuf[r * HS2 + lane] = make_float2(q0 - P0, q1 - P1);
        }
    }
    __syncthreads();

    const float* g0 = guide + (size_t)b * 3 * PLANE;
    const int base = (vq * 4) * HS2 + c31;
    float s0 = 0.f, s1 = 0.f;
    #pragma unroll
    for (int k = 0; k < 31; ++k) { float2 v = hbuf[base + k * HS2]; s0 += v.x; s1 += v.y; }
    float* op = out + (size_t)bc * PLANE;
    #pragma unroll
    for (int j = 0; j < 4; ++j) {
        if (j) {
            float2 vi = hbuf[base + (j + 30) * HS2], vo = hbuf[base + (j - 1) * HS2];
            s0 += vi.x - vo.x; s1 += vi.y - vo.y;
        }
        int o = (ty0 + vq * 4 + j) * HW + tx0 + c31;
        float gray = 0.299f * g0[o] + 0.587f * g0[PLANE + o] + 0.114f * g0[2 * PLANE + o];
        op[o] = s0 * INV_K2 * gray + s1 * INV_K2;
    }
}

extern "C" void kernel_launch(void* const* d_in, const int* in_sizes, int n_in,
                              void* d_out, int out_size, void* d_ws, size_t ws_size,
                              hipStream_t stream)
{
    const float* guide = (const float*)d_in[0];
    const float* inp   = (const float*)d_in[1];
    float* out  = (float*)d_out;

    float2* ab_ws = (float2*)d_ws;   // 24 planes of interleaved {a,b} = 50.3 MB

    dim3 block(256);
    dim3 grid1(HW / TILE, HW / TILE, 8);
    gf_stage1<<<grid1, block, 0, stream>>>(guide, inp, ab_ws);

    dim3 grid2(HW / TILE, HW / TILE, 24);
    gf_stage2<<<grid2, block, 0, stream>>>(guide, ab_ws, out);
}